// Round 3
// baseline (878.669 us; speedup 1.0000x reference)
//
#include <hip/hip_runtime.h>
#include <hip/hip_cooperative_groups.h>
#include <hip/hip_bf16.h>

namespace cg = cooperative_groups;

typedef _Float16 half8 __attribute__((ext_vector_type(8)));
typedef float floatx4 __attribute__((ext_vector_type(4)));

#define SEQ 2048
#define DIM 2048
#define HQ 32
#define HKV 8
#define HD 64
#define NQ (HQ*HD)    /* 2048 */
#define NK (HKV*HD)   /* 512  */
#define NTOT (NQ+NK)  /* 2560 */
#define LOG2E 1.44269504088896340736f

#define GLOAD_LDS16(g, l) \
    __builtin_amdgcn_global_load_lds( \
        (const __attribute__((address_space(1))) void*)(g), \
        (__attribute__((address_space(3))) void*)(l), 16, 0, 0)

// ---------------------------------------------------------------------------
// Single cooperative kernel, 256 blocks x 512 threads, 1 block/CU (128 KB LDS).
// Phase A: fp32->fp16 convert (grid-stride).
// Phase B: QK projection GEMM + RoPE, 128x128 tiles (320 tiles, <=2/block),
//          global_load_lds staging with XOR chunk swizzle, 8 waves (4x2 grid,
//          wave tile 32x64 so each wave covers one full head for RoPE).
// Phase C: scores + softmax, 8 (qb,h) units per block; operand-swapped MFMA,
//          K reused across two 16-row q-groups, output via per-wave XOR LDS
//          transpose -> 1 KB contiguous nontemporal stores.
// grid.sync() + __threadfence() between phases (cross-XCD visibility).
// ---------------------------------------------------------------------------
__global__ __launch_bounds__(512, 2) void fused_kernel(
    const float* __restrict__ X, const float* __restrict__ cosb,
    const float* __restrict__ sinb, const float* __restrict__ Wq,
    const float* __restrict__ Wk, float* __restrict__ out,
    _Float16* __restrict__ Xh, _Float16* __restrict__ Wh,
    _Float16* __restrict__ qf, _Float16* __restrict__ kf)
{
    __shared__ __align__(16) float lsT[8][16][256];   // 128 KB, phase-unioned
    cg::grid_group grid = cg::this_grid();
    const int tid  = threadIdx.x;
    const int bid  = blockIdx.x;
    const int lane = tid & 63;
    const int wv   = tid >> 6;
    const int m    = lane & 15, quad = lane >> 4;

    // ---------------- Phase A: convert ----------------
    {
        const long nxc  = (long)SEQ * DIM / 8;           // 524288 chunks (X)
        const long nall = nxc + (long)NTOT * DIM / 8;    // 1179648 total
        for (long c = (long)bid * 512 + tid; c < nall; c += 131072) {
            const float* src; _Float16* dst;
            if (c < nxc) { src = X + c * 8; dst = Xh + c * 8; }
            else {
                long f = (c - nxc) * 8;
                src = (f < (long)NQ * DIM) ? Wq + f : Wk + (f - (long)NQ * DIM);
                dst = Wh + f;
            }
            float4 a = ((const float4*)src)[0];
            float4 b = ((const float4*)src)[1];
            half8 h = {(_Float16)a.x, (_Float16)a.y, (_Float16)a.z, (_Float16)a.w,
                       (_Float16)b.x, (_Float16)b.y, (_Float16)b.z, (_Float16)b.w};
            *(half8*)dst = h;
        }
    }
    __threadfence();
    grid.sync();

    // ---------------- Phase B: GEMM + RoPE ----------------
    {
        _Float16* lsA = (_Float16*)&lsT[0][0][0];   // 16 KB
        _Float16* lsB = lsA + 128 * 64;             // 16 KB
        const int wm = wv >> 1;   // 0..3, 32-row stripe
        const int wn = wv & 1;    // 0..1, 64-col stripe (= one head)
        for (int t = bid; t < 320; t += 256) {
            const int s0 = (t & 15) * 128;
            const int n0 = (t >> 4) * 128;
            floatx4 acc[2][4];
            #pragma unroll
            for (int i = 0; i < 2; i++)
                #pragma unroll
                for (int j = 0; j < 4; j++)
                    acc[i][j] = floatx4{0.f, 0.f, 0.f, 0.f};

            for (int k0 = 0; k0 < DIM; k0 += 64) {
                __syncthreads();
                // A tile: 128 rows x 8 chunks = 1024 chunks, 2 rounds of 512
                #pragma unroll
                for (int r = 0; r < 2; r++) {
                    int c   = r * 512 + tid;
                    int row = c >> 3;
                    int chg = (c & 7) ^ (row & 7);
                    GLOAD_LDS16(Xh + (long)(s0 + row) * DIM + k0 + chg * 8,
                                (char*)lsA + (r * 512 + wv * 64) * 16);
                }
                // B tile: 128 rows x 8 chunks = 1024 chunks, 2 rounds
                #pragma unroll
                for (int r = 0; r < 2; r++) {
                    int c   = r * 512 + tid;
                    int row = c >> 3;
                    int chg = (c & 7) ^ (row & 7);
                    GLOAD_LDS16(Wh + (long)(n0 + row) * DIM + k0 + chg * 8,
                                (char*)lsB + (r * 512 + wv * 64) * 16);
                }
                __syncthreads();

                #pragma unroll
                for (int kk = 0; kk < 2; kk++) {
                    half8 aF[2], bF[4];
                    const int pc = ((kk << 2) | quad) ^ (m & 7);
                    #pragma unroll
                    for (int i = 0; i < 2; i++)
                        aF[i] = *(const half8*)(lsA + (wm * 32 + i * 16 + m) * 64 + pc * 8);
                    #pragma unroll
                    for (int j = 0; j < 4; j++)
                        bF[j] = *(const half8*)(lsB + (wn * 64 + j * 16 + m) * 64 + pc * 8);
                    #pragma unroll
                    for (int i = 0; i < 2; i++)
                        #pragma unroll
                        for (int j = 0; j < 4; j++)
                            acc[i][j] = __builtin_amdgcn_mfma_f32_16x16x32_f16(
                                aF[i], bF[j], acc[i][j], 0, 0, 0);
                }
            }

            // Epilogue: RoPE + fp16 store (wave covers one full head).
            #pragma unroll
            for (int i = 0; i < 2; i++) {
                #pragma unroll
                for (int reg = 0; reg < 4; reg++) {
                    int s = s0 + wm * 32 + i * 16 + quad * 4 + reg;
                    #pragma unroll
                    for (int j = 0; j < 4; j++) {
                        int col = n0 + wn * 64 + j * 16 + m;
                        int d   = j * 16 + m;
                        float v = acc[i][j][reg];
                        float partner = (j < 2) ? -acc[i][j + 2][reg] : acc[i][j - 2][reg];
                        float cs = cosb[s * HD + d];
                        float sn = sinb[s * HD + d];
                        float o  = v * cs + partner * sn;
                        if (col < NQ) {
                            int hq = col >> 6;
                            qf[((long)hq * SEQ + s) * HD + d] = (_Float16)(o * LOG2E);
                        } else {
                            int hk = (col - NQ) >> 6;
                            kf[((long)hk * SEQ + s) * HD + d] = (_Float16)o;
                        }
                    }
                }
            }
        }
    }
    __threadfence();
    grid.sync();

    // ---------------- Phase C: scores + softmax ----------------
    {
        float* redm = &lsT[0][0][0];    // [2][8][16] floats
        float* redl = redm + 256;       // [2][8][16] floats
        const int w = wv;               // wave owns keys [w*256, w*256+256)

        for (int u = 0; u < 8; u++) {
            __syncthreads();   // protect lsT reuse across units
            const int unit = u * 256 + bid;   // 0..2047
            const int qb   = unit & 63;
            const int h    = unit >> 6;
            const int kvh  = h >> 2;
            const int s0   = qb * 32;

            const _Float16* qbase = qf + ((long)h * SEQ + s0) * HD;
            const _Float16* kbase = kf + (long)kvh * SEQ * HD;

            half8 bQ[2][2];
            #pragma unroll
            for (int g = 0; g < 2; g++) {
                bQ[g][0] = *(const half8*)(qbase + (long)(g * 16 + m) * HD + quad * 8);
                bQ[g][1] = *(const half8*)(qbase + (long)(g * 16 + m) * HD + 32 + quad * 8);
            }

            floatx4 acc[2][16];
            const _Float16* kp = kbase + (long)(w * 256 + m) * HD + quad * 8;
            half8 aK0 = *(const half8*)(kp);
            half8 aK1 = *(const half8*)(kp + 32);
            #pragma unroll
            for (int ct = 0; ct < 16; ct++) {
                half8 nK0, nK1;
                if (ct < 15) {
                    const _Float16* np = kbase + (long)(w * 256 + (ct + 1) * 16 + m) * HD + quad * 8;
                    nK0 = *(const half8*)(np);
                    nK1 = *(const half8*)(np + 32);
                }
                #pragma unroll
                for (int g = 0; g < 2; g++) {
                    floatx4 a = floatx4{0.f, 0.f, 0.f, 0.f};
                    a = __builtin_amdgcn_mfma_f32_16x16x32_f16(aK0, bQ[g][0], a, 0, 0, 0);
                    a = __builtin_amdgcn_mfma_f32_16x16x32_f16(aK1, bQ[g][1], a, 0, 0, 0);
                    acc[g][ct] = a;
                }
                aK0 = nK0;
                aK1 = nK1;
            }

            // softmax
            float gmax[2];
            #pragma unroll
            for (int g = 0; g < 2; g++) {
                float lm = acc[g][0][0];
                #pragma unroll
                for (int ct = 0; ct < 16; ct++)
                    #pragma unroll
                    for (int r = 0; r < 4; r++) lm = fmaxf(lm, acc[g][ct][r]);
                lm = fmaxf(lm, __shfl_xor(lm, 16));
                lm = fmaxf(lm, __shfl_xor(lm, 32));
                if (quad == 0) redm[(g * 8 + w) * 16 + m] = lm;
            }
            __syncthreads();
            #pragma unroll
            for (int g = 0; g < 2; g++) {
                float gm = redm[(g * 8 + 0) * 16 + m];
                #pragma unroll
                for (int ww = 1; ww < 8; ww++)
                    gm = fmaxf(gm, redm[(g * 8 + ww) * 16 + m]);
                gmax[g] = gm;
            }

            float inv_[2];
            #pragma unroll
            for (int g = 0; g < 2; g++) {
                float ls = 0.f;
                #pragma unroll
                for (int ct = 0; ct < 16; ct++) {
                    #pragma unroll
                    for (int r = 0; r < 4; r++) {
                        float e = exp2f(acc[g][ct][r] - gmax[g]);  // Q pre-scaled
                        acc[g][ct][r] = e;
                        ls += e;
                    }
                }
                ls += __shfl_xor(ls, 16);
                ls += __shfl_xor(ls, 32);
                if (quad == 0) redl[(g * 8 + w) * 16 + m] = ls;
            }
            __syncthreads();
            #pragma unroll
            for (int g = 0; g < 2; g++) {
                float tot = 0.f;
                #pragma unroll
                for (int ww = 0; ww < 8; ww++) tot += redl[(g * 8 + ww) * 16 + m];
                inv_[g] = 1.0f / tot;
            }
            __syncthreads();   // done reading redm/redl before lsT overwrite

            // store via per-wave LDS transpose -> 1 KB contiguous NT stores
            #pragma unroll
            for (int g = 0; g < 2; g++) {
                #pragma unroll
                for (int ct = 0; ct < 16; ct++) {
                    floatx4 v = acc[g][ct];
                    v[0] *= inv_[g]; v[1] *= inv_[g]; v[2] *= inv_[g]; v[3] *= inv_[g];
                    int slot = (ct * 4 + quad) ^ m;
                    *(floatx4*)&lsT[w][m][slot * 4] = v;
                }
                #pragma unroll
                for (int r = 0; r < 16; r++) {
                    int slot = lane ^ r;
                    floatx4 v = *(const floatx4*)&lsT[w][r][slot * 4];
                    float* dst = out + ((long)h * SEQ + s0 + g * 16 + r) * SEQ
                                     + w * 256 + lane * 4;
                    __builtin_nontemporal_store(v, (floatx4*)dst);
                }
            }
        }
    }
}

// ---------------------------------------------------------------------------
extern "C" void kernel_launch(void* const* d_in, const int* in_sizes, int n_in,
                              void* d_out, int out_size, void* d_ws, size_t ws_size,
                              hipStream_t stream) {
    const float* hidden = (const float*)d_in[0];
    const float* cosb   = (const float*)d_in[1];
    const float* sinb   = (const float*)d_in[2];
    // d_in[3] = attn_mask (all zeros, unused by reference) — ignored
    const float* Wq     = (const float*)d_in[4];
    const float* Wk     = (const float*)d_in[5];
    float* out = (float*)d_out;

    char* ws = (char*)d_ws;
    _Float16* Xh = (_Float16*)ws;                                   // 8 MiB
    _Float16* Wh = (_Float16*)(ws + 8388608);                       // 10 MiB
    _Float16* qf = (_Float16*)(ws + 8388608 + 10485760);            // 8 MiB
    _Float16* kf = (_Float16*)(ws + 8388608 + 10485760 + 8388608);  // 2 MiB

    void* args[] = {(void*)&hidden, (void*)&cosb, (void*)&sinb, (void*)&Wq,
                    (void*)&Wk, (void*)&out, (void*)&Xh, (void*)&Wh,
                    (void*)&qf, (void*)&kf};
    hipLaunchCooperativeKernel((const void*)fused_kernel, dim3(256), dim3(512),
                               args, 0, stream);
}